// Round 1
// baseline (315.176 us; speedup 1.0000x reference)
//
#include <hip/hip_runtime.h>
#include <hip/hip_bf16.h>

// Problem constants (match reference setup_inputs)
#define B    64
#define OBJS 2048
#define NTOT (B * OBJS)     // 131072
#define D    256
#define K    2

// Blocks per scene for the two heavy passes
#define S1 16
#define S2 16
#define CH1 (OBJS / S1)     // 128 rows per block
#define CH2 (OBJS / S2)

// Workspace layout (in floats)
//  ctx_sum : B*D      per-scene column sums
//  U       : B*D*K    unnormalized weighted feature sums, layout (b*D+d)*K+k
//  Z       : B*K      sum of exp per scene/channel
//  bt      : K        channel_bias @ att_shared (padded to 64)
//  e       : NTOT*K   unnormalized exp(logit) per row (float2 per row)
#define WS_CTX 0
#define WS_U   (B * D)
#define WS_Z   (WS_U + B * D * K)
#define WS_BT  (WS_Z + B * K)
#define WS_E   (WS_BT + 64)            // 49344 floats -> 8B-aligned for float2
#define WS_ZERO_FLOATS (B * D + B * D * K + B * K)

static __device__ __forceinline__ float lrelu02(float v) {
    return v > 0.0f ? v : 0.2f * v;
}

// ---- prep: bias_term[k] = channel_bias[k,:] . att_shared[0,:] ----
__global__ void prep_bt_kernel(const float* __restrict__ att_shared,
                               const float* __restrict__ channel_bias,
                               float* __restrict__ ws) {
    int l = threadIdx.x;  // 64 lanes, one wave
    float4 a = ((const float4*)att_shared)[l];
#pragma unroll
    for (int k = 0; k < K; ++k) {
        float4 c = ((const float4*)(channel_bias + k * D))[l];
        float v = a.x * c.x + a.y * c.y + a.z * c.z + a.w * c.w;
#pragma unroll
        for (int m = 32; m > 0; m >>= 1) v += __shfl_xor(v, m);
        if (l == 0) ws[WS_BT + k] = v;
    }
}

// ---- pass 1: per-scene column sums (ctx numerator) ----
// wave-per-row: lane l holds columns 4l..4l+3 as float4 (fully coalesced 1 KiB/row)
__global__ __launch_bounds__(256) void k1_ctx_kernel(const float* __restrict__ x,
                                                     float* __restrict__ ws) {
    int b = blockIdx.x / S1;
    int c = blockIdx.x % S1;
    int w = threadIdx.x >> 6;
    int l = threadIdx.x & 63;
    int row0 = b * OBJS + c * CH1;

    float4 acc = make_float4(0.f, 0.f, 0.f, 0.f);
    for (int i = w; i < CH1; i += 4) {
        float4 v = *(const float4*)(x + (size_t)(row0 + i) * D + 4 * l);
        acc.x += v.x; acc.y += v.y; acc.z += v.z; acc.w += v.w;
    }
    float* ctx = ws + WS_CTX + b * D + 4 * l;
    atomicAdd(ctx + 0, acc.x);
    atomicAdd(ctx + 1, acc.y);
    atomicAdd(ctx + 2, acc.z);
    atomicAdd(ctx + 3, acc.w);
}

// ---- pass 2: base -> e -> accumulate U (x-weighted) and Z, store e ----
__global__ __launch_bounds__(256) void k2_main_kernel(const float* __restrict__ x,
                                                      const int* __restrict__ num_objs,
                                                      const float* __restrict__ att_scale,
                                                      const float* __restrict__ att_shared,
                                                      float* __restrict__ ws) {
    int b = blockIdx.x / S2;
    int c = blockIdx.x % S2;
    int w = threadIdx.x >> 6;
    int l = threadIdx.x & 63;
    int row0 = b * OBJS + c * CH2;

    int cnt = num_objs[b]; if (cnt < 1) cnt = 1;
    float inv_cnt = 1.0f / (float)cnt;

    // hoisted per-scene / per-lane constants
    float4 a4 = ((const float4*)att_shared)[l];
    float4 ctx4 = *(const float4*)(ws + WS_CTX + b * D + 4 * l);
    ctx4.x *= inv_cnt; ctx4.y *= inv_cnt; ctx4.z *= inv_cnt; ctx4.w *= inv_cnt;
    float bt0 = ws[WS_BT + 0], bt1 = ws[WS_BT + 1];
    float s0 = att_scale[0],   s1 = att_scale[1];

    float4 acc0 = make_float4(0.f, 0.f, 0.f, 0.f);
    float4 acc1 = make_float4(0.f, 0.f, 0.f, 0.f);
    float z0 = 0.f, z1 = 0.f;
    float2* ews = (float2*)(ws + WS_E);

    for (int i = w; i < CH2; i += 4) {
        int r = row0 + i;
        float4 v = *(const float4*)(x + (size_t)r * D + 4 * l);
        float p = lrelu02(v.x + ctx4.x) * a4.x
                + lrelu02(v.y + ctx4.y) * a4.y
                + lrelu02(v.z + ctx4.z) * a4.z
                + lrelu02(v.w + ctx4.w) * a4.w;
#pragma unroll
        for (int m = 32; m > 0; m >>= 1) p += __shfl_xor(p, m);  // all-lanes base
        float e0 = expf((p + bt0) * s0);
        float e1 = expf((p + bt1) * s1);
        acc0.x += v.x * e0; acc0.y += v.y * e0; acc0.z += v.z * e0; acc0.w += v.w * e0;
        acc1.x += v.x * e1; acc1.y += v.y * e1; acc1.z += v.z * e1; acc1.w += v.w * e1;
        if (l == 0) {
            z0 += e0; z1 += e1;
            ews[r] = make_float2(e0, e1);
        }
    }

    if (l == 0) {
        atomicAdd(ws + WS_Z + b * K + 0, z0);
        atomicAdd(ws + WS_Z + b * K + 1, z1);
    }
    // U layout (b*D + d)*K + k with d = 4l+j
    float* U = ws + WS_U + (size_t)(b * D + 4 * l) * K;
    atomicAdd(U + 0, acc0.x); atomicAdd(U + 1, acc1.x);
    atomicAdd(U + 2, acc0.y); atomicAdd(U + 3, acc1.y);
    atomicAdd(U + 4, acc0.z); atomicAdd(U + 5, acc1.z);
    atomicAdd(U + 6, acc0.w); atomicAdd(U + 7, acc1.w);
}

// ---- pass 3: normalize -> writes ALL of d_out ----
__global__ __launch_bounds__(256) void k3_final_kernel(const float* __restrict__ ws,
                                                       float* __restrict__ out) {
    int i = blockIdx.x * blockDim.x + threadIdx.x;
    const int FEAT = B * D * K;  // 32768
    if (i < FEAT) {
        int b = i / (D * K);
        int k = i & (K - 1);
        out[i] = ws[WS_U + i] / ws[WS_Z + b * K + k];
    } else {
        int r = i - FEAT;
        if (r < NTOT) {
            int b = r / OBJS;
            float2 e = ((const float2*)(ws + WS_E))[r];
            float z0 = ws[WS_Z + b * K + 0];
            float z1 = ws[WS_Z + b * K + 1];
            ((float2*)(out + FEAT))[r] = make_float2(e.x / z0, e.y / z1);
        }
    }
}

extern "C" void kernel_launch(void* const* d_in, const int* in_sizes, int n_in,
                              void* d_out, int out_size, void* d_ws, size_t ws_size,
                              hipStream_t stream) {
    const float* x            = (const float*)d_in[0];   // [N, D]
    const int*   num_objs     = (const int*)d_in[1];     // [B]
    const float* att_shared   = (const float*)d_in[2];   // [1, D]
    const float* att_scale    = (const float*)d_in[3];   // [K, 1]
    const float* channel_bias = (const float*)d_in[4];   // [K, D]
    float* ws  = (float*)d_ws;
    float* out = (float*)d_out;

    // zero the accumulators (ctx_sum, U, Z); d_out is fully written by k3
    hipMemsetAsync(d_ws, 0, (size_t)WS_ZERO_FLOATS * sizeof(float), stream);

    prep_bt_kernel<<<1, 64, 0, stream>>>(att_shared, channel_bias, ws);
    k1_ctx_kernel<<<B * S1, 256, 0, stream>>>(x, ws);
    k2_main_kernel<<<B * S2, 256, 0, stream>>>(x, num_objs, att_scale, att_shared, ws);

    const int total = B * D * K + NTOT;           // 163840
    k3_final_kernel<<<(total + 255) / 256, 256, 0, stream>>>(ws, out);
}

// Round 2
// 227.343 us; speedup vs baseline: 1.3863x; 1.3863x over previous
//
#include <hip/hip_runtime.h>

// Problem constants (match reference setup_inputs)
#define B    64
#define OBJS 2048
#define NTOT (B * OBJS)       // 131072
#define D    256
#define K    2
#define S1   16               // blocks per scene for heavy passes
#define CH   (OBJS / S1)      // 128 rows per block
#define RPW  (CH / 4)         // 32 rows per wave (contiguous chunk)

// Workspace layout (floats). UP aliases P1 (P1 dead after k1b; stream-ordered).
#define WS_UP  0              // 1024 * 512  (k2 partial U)         = 524288
#define WS_P1  0              // 1024 * 256  (k1 partial ctx sums)  = 262144
#define WS_CTX 524288         // B*D   per-scene mean (pre-divided)
#define WS_BT  540672         // K     channel_bias @ att_shared (pad to 64)
#define WS_ZP  540736         // 1024 blocks * 4 waves * K = 8192
#define WS_Z   548928         // B*K
#define WS_E   549056         // NTOT*K  (16B-aligned)
// total = 811200 floats ~= 3.2 MB

static __device__ __forceinline__ float lrelu02(float v) {
    return v > 0.0f ? v : 0.2f * v;
}

// ---- pass 1: per-block partial column sums, NO atomics ----
__global__ __launch_bounds__(256) void k1_partial(const float* __restrict__ x,
                                                  float* __restrict__ ws) {
    __shared__ float red[4 * D];
    int blk = blockIdx.x;
    int b = blk >> 4, c = blk & 15;
    int w = threadIdx.x >> 6, l = threadIdx.x & 63;
    int row0 = b * OBJS + c * CH + w * RPW;

    float4 acc = make_float4(0.f, 0.f, 0.f, 0.f);
    const float* px = x + (size_t)row0 * D + 4 * l;
#pragma unroll 4
    for (int j = 0; j < RPW; ++j) {
        float4 v = *(const float4*)(px + (size_t)j * D);
        acc.x += v.x; acc.y += v.y; acc.z += v.z; acc.w += v.w;
    }
    *(float4*)(red + w * D + 4 * l) = acc;
    __syncthreads();
    int t = threadIdx.x;
    if (t < 64) {
        float4 a = ((const float4*)(red        ))[t];
        float4 e = ((const float4*)(red +     D))[t];
        float4 f = ((const float4*)(red + 2 * D))[t];
        float4 g = ((const float4*)(red + 3 * D))[t];
        float4 s = make_float4(a.x + e.x + f.x + g.x, a.y + e.y + f.y + g.y,
                               a.z + e.z + f.z + g.z, a.w + e.w + f.w + g.w);
        *(float4*)(ws + WS_P1 + blk * D + 4 * t) = s;
    }
}

// ---- reduce partials -> ctx mean; block 0 wave 0 also computes bias_term ----
__global__ __launch_bounds__(256) void k1b_reduce(const float* __restrict__ att_shared,
                                                  const float* __restrict__ channel_bias,
                                                  const int* __restrict__ num_objs,
                                                  float* __restrict__ ws) {
    int b = blockIdx.x, t = threadIdx.x;
    int cnt = num_objs[b]; if (cnt < 1) cnt = 1;
    float inv = 1.0f / (float)cnt;
    float s = 0.f;
#pragma unroll
    for (int c = 0; c < S1; ++c) s += ws[WS_P1 + (b * S1 + c) * D + t];
    ws[WS_CTX + b * D + t] = s * inv;

    if (b == 0 && t < 64) {
        float4 a = ((const float4*)att_shared)[t];
#pragma unroll
        for (int k = 0; k < K; ++k) {
            float4 cb = ((const float4*)(channel_bias + k * D))[t];
            float v = a.x * cb.x + a.y * cb.y + a.z * cb.z + a.w * cb.w;
#pragma unroll
            for (int m = 32; m > 0; m >>= 1) v += __shfl_xor(v, m);
            if (t == 0) ws[WS_BT + k] = v;
        }
    }
}

// ---- pass 2: base -> e -> partial U/Z (plain stores), e stored coalesced ----
__global__ __launch_bounds__(256) void k2_main(const float* __restrict__ x,
                                               const float* __restrict__ att_scale,
                                               const float* __restrict__ att_shared,
                                               float* __restrict__ ws) {
    __shared__ float ured[4 * D * K];   // 8 KB
    int blk = blockIdx.x;
    int b = blk >> 4, c = blk & 15;
    int w = threadIdx.x >> 6, l = threadIdx.x & 63;
    int row0 = b * OBJS + c * CH + w * RPW;   // contiguous 32-row chunk per wave

    float4 a4 = ((const float4*)att_shared)[l];
    float4 ctx4 = *(const float4*)(ws + WS_CTX + b * D + 4 * l);
    float bt0 = ws[WS_BT + 0], bt1 = ws[WS_BT + 1];
    float s0 = att_scale[0],   s1 = att_scale[1];

    float4 acc0 = make_float4(0.f, 0.f, 0.f, 0.f);
    float4 acc1 = make_float4(0.f, 0.f, 0.f, 0.f);
    float z0 = 0.f, z1 = 0.f;
    float my_e0 = 0.f, my_e1 = 0.f;
    int sel = l & 31;
    const float* px = x + (size_t)row0 * D + 4 * l;

#pragma unroll 2
    for (int j = 0; j < RPW; ++j) {
        float4 v = *(const float4*)(px + (size_t)j * D);
        float p = lrelu02(v.x + ctx4.x) * a4.x
                + lrelu02(v.y + ctx4.y) * a4.y
                + lrelu02(v.z + ctx4.z) * a4.z
                + lrelu02(v.w + ctx4.w) * a4.w;
#pragma unroll
        for (int m = 32; m > 0; m >>= 1) p += __shfl_xor(p, m);
        float e0 = __expf((p + bt0) * s0);
        float e1 = __expf((p + bt1) * s1);
        z0 += e0; z1 += e1;                      // identical on all lanes
        acc0.x += v.x * e0; acc0.y += v.y * e0; acc0.z += v.z * e0; acc0.w += v.w * e0;
        acc1.x += v.x * e1; acc1.y += v.y * e1; acc1.z += v.z * e1; acc1.w += v.w * e1;
        if (j == sel) { my_e0 = e0; my_e1 = e1; }
    }

    // batched coalesced e store: lanes 0..31 hold rows row0..row0+31
    if (l < 32) ((float2*)(ws + WS_E))[row0 + l] = make_float2(my_e0, my_e1);
    // per-wave Z partial
    if (l == 0) {
        ws[WS_ZP + blk * 8 + w * 2 + 0] = z0;
        ws[WS_ZP + blk * 8 + w * 2 + 1] = z1;
    }
    // cross-wave U reduce in LDS, one coalesced 2 KB store per block
    int base = w * (D * K) + l * 8;   // column index (4l+j)*2+k within wave region
    ured[base + 0] = acc0.x; ured[base + 1] = acc1.x;
    ured[base + 2] = acc0.y; ured[base + 3] = acc1.y;
    ured[base + 4] = acc0.z; ured[base + 5] = acc1.z;
    ured[base + 6] = acc0.w; ured[base + 7] = acc1.w;
    __syncthreads();
    int t = threadIdx.x;
    if (t < 128) {
        float4 a = ((const float4*)(ured       ))[t];
        float4 e = ((const float4*)(ured +  512))[t];
        float4 f = ((const float4*)(ured + 1024))[t];
        float4 g = ((const float4*)(ured + 1536))[t];
        float4 s = make_float4(a.x + e.x + f.x + g.x, a.y + e.y + f.y + g.y,
                               a.z + e.z + f.z + g.z, a.w + e.w + f.w + g.w);
        *(float4*)(ws + WS_UP + blk * (D * K) + 4 * t) = s;
    }
}

// ---- reduce Z partials: 128 threads, one (b,k) each ----
__global__ void kz_reduce(float* __restrict__ ws) {
    int t = threadIdx.x;
    int b = t >> 1, k = t & 1;
    float s = 0.f;
    for (int c = 0; c < S1; ++c)
#pragma unroll
        for (int w = 0; w < 4; ++w)
            s += ws[WS_ZP + (b * S1 + c) * 8 + w * 2 + k];
    ws[WS_Z + t] = s;
}

// ---- finalize: features = sum(UP)/Z ; weights = e/Z (writes ALL of d_out) ----
__global__ __launch_bounds__(256) void k3_final(const float* __restrict__ ws,
                                                float* __restrict__ out) {
    int i = blockIdx.x * 256 + threadIdx.x;
    const int FEAT = B * D * K;   // 32768, layout b*512 + d*2 + k
    if (i < FEAT) {
        int b = i >> 9;
        int j = i & 511;
        int k = i & 1;
        float s = 0.f;
#pragma unroll
        for (int c = 0; c < S1; ++c) s += ws[WS_UP + (b * S1 + c) * 512 + j];
        out[i] = s / ws[WS_Z + b * K + k];
    } else {
        int r = i - FEAT;
        if (r < NTOT) {
            int b = r >> 11;   // OBJS = 2048
            float2 e = ((const float2*)(ws + WS_E))[r];
            float z0 = ws[WS_Z + b * K + 0];
            float z1 = ws[WS_Z + b * K + 1];
            ((float2*)(out + FEAT))[r] = make_float2(e.x / z0, e.y / z1);
        }
    }
}

extern "C" void kernel_launch(void* const* d_in, const int* in_sizes, int n_in,
                              void* d_out, int out_size, void* d_ws, size_t ws_size,
                              hipStream_t stream) {
    const float* x            = (const float*)d_in[0];   // [N, D]
    const int*   num_objs     = (const int*)d_in[1];     // [B]
    const float* att_shared   = (const float*)d_in[2];   // [1, D]
    const float* att_scale    = (const float*)d_in[3];   // [K, 1]
    const float* channel_bias = (const float*)d_in[4];   // [K, D]
    float* ws  = (float*)d_ws;
    float* out = (float*)d_out;

    // no memset needed: every ws/out location is written before it is read
    k1_partial<<<B * S1, 256, 0, stream>>>(x, ws);
    k1b_reduce<<<B, 256, 0, stream>>>(att_shared, channel_bias, num_objs, ws);
    k2_main<<<B * S1, 256, 0, stream>>>(x, att_scale, att_shared, ws);
    kz_reduce<<<1, 128, 0, stream>>>(ws);
    const int total = B * D * K + NTOT;   // 163840
    k3_final<<<(total + 255) / 256, 256, 0, stream>>>(ws, out);
}

// Round 3
// 222.793 us; speedup vs baseline: 1.4147x; 1.0204x over previous
//
#include <hip/hip_runtime.h>

// Problem constants (match reference setup_inputs)
#define B    64
#define OBJS 2048
#define NTOT (B * OBJS)       // 131072
#define D    256
#define K    2
#define S1   16               // blocks per scene for heavy passes
#define CH   (OBJS / S1)      // 128 rows per block
#define RPW  (CH / 4)         // 32 rows per wave (contiguous chunk)

// Workspace layout (floats); ws is far larger than needed (512 MiB).
#define WS_P1  0                          // 1024 * 256  k1 partial ctx sums
#define WS_UP  (1024 * 256)               // 1024 * 512  k2 partial U
#define WS_ZP  (WS_UP + 1024 * 512)       // 1024 * 8    k2 partial Z
#define WS_E   (WS_ZP + 1024 * 8)         // NTOT * 2    exp(logit) per row (16B aligned)

static __device__ __forceinline__ float lrelu02(float v) {
    return v > 0.0f ? v : 0.2f * v;
}

// ---- pass 1: per-block partial column sums of x (streams 128 MiB from HBM) ----
__global__ __launch_bounds__(256) void k1_partial(const float* __restrict__ x,
                                                  float* __restrict__ ws) {
    __shared__ float red[4 * D];
    int blk = blockIdx.x;                      // scenes contiguous: rows blk*CH ..
    int w = threadIdx.x >> 6, l = threadIdx.x & 63;
    int row0 = blk * CH + w * RPW;

    float4 acc = make_float4(0.f, 0.f, 0.f, 0.f);
    const float* px = x + (size_t)row0 * D + 4 * l;
#pragma unroll 8
    for (int j = 0; j < RPW; ++j) {
        float4 v = *(const float4*)(px + (size_t)j * D);
        acc.x += v.x; acc.y += v.y; acc.z += v.z; acc.w += v.w;
    }
    *(float4*)(red + w * D + 4 * l) = acc;
    __syncthreads();
    int t = threadIdx.x;
    if (t < 64) {
        float4 a = ((const float4*)(red        ))[t];
        float4 e = ((const float4*)(red +     D))[t];
        float4 f = ((const float4*)(red + 2 * D))[t];
        float4 g = ((const float4*)(red + 3 * D))[t];
        float4 s = make_float4(a.x + e.x + f.x + g.x, a.y + e.y + f.y + g.y,
                               a.z + e.z + f.z + g.z, a.w + e.w + f.w + g.w);
        *(float4*)(ws + WS_P1 + blk * D + 4 * t) = s;
    }
}

// ---- pass 2: inline ctx/bias reduce -> base -> e -> partial U/Z ----
__global__ __launch_bounds__(256) void k2_main(const float* __restrict__ x,
                                               const int* __restrict__ num_objs,
                                               const float* __restrict__ att_scale,
                                               const float* __restrict__ att_shared,
                                               const float* __restrict__ channel_bias,
                                               float* __restrict__ ws) {
    __shared__ float sctx[D];
    __shared__ float sbt[2];
    __shared__ float ured[4 * D * K];   // 8 KB
    int blk = blockIdx.x;
    int b = blk >> 4;
    int t = threadIdx.x;
    int w = t >> 6, l = t & 63;
    int row0 = blk * CH + w * RPW;      // contiguous 32-row chunk per wave

    // prologue A: reduce this scene's 16 ctx partials (16 KB, L2/L3-hit)
    {
        int cnt = num_objs[b]; if (cnt < 1) cnt = 1;
        float inv = 1.0f / (float)cnt;
        float s = 0.f;
#pragma unroll
        for (int c = 0; c < S1; ++c) s += ws[WS_P1 + (b * S1 + c) * D + t];
        sctx[t] = s * inv;
    }
    // prologue B: bias_term[k] = channel_bias[k,:] . att_shared  (wave 0)
    if (t < 64) {
        float4 a = ((const float4*)att_shared)[t];
#pragma unroll
        for (int k = 0; k < K; ++k) {
            float4 cb = ((const float4*)(channel_bias + k * D))[t];
            float v = a.x * cb.x + a.y * cb.y + a.z * cb.z + a.w * cb.w;
#pragma unroll
            for (int m = 32; m > 0; m >>= 1) v += __shfl_xor(v, m);
            if (t == 0) sbt[k] = v;
        }
    }
    __syncthreads();

    float4 a4 = ((const float4*)att_shared)[l];
    float4 ctx4 = *(const float4*)(sctx + 4 * l);
    float bt0 = sbt[0], bt1 = sbt[1];
    float s0 = att_scale[0], s1 = att_scale[1];

    float4 acc0 = make_float4(0.f, 0.f, 0.f, 0.f);
    float4 acc1 = make_float4(0.f, 0.f, 0.f, 0.f);
    float z0 = 0.f, z1 = 0.f;
    float my_e0 = 0.f, my_e1 = 0.f;
    int sel = l & 31;
    const float* px = x + (size_t)row0 * D + 4 * l;

#pragma unroll 4
    for (int j = 0; j < RPW; ++j) {
        float4 v = *(const float4*)(px + (size_t)j * D);
        float p = lrelu02(v.x + ctx4.x) * a4.x
                + lrelu02(v.y + ctx4.y) * a4.y
                + lrelu02(v.z + ctx4.z) * a4.z
                + lrelu02(v.w + ctx4.w) * a4.w;
#pragma unroll
        for (int m = 32; m > 0; m >>= 1) p += __shfl_xor(p, m);  // all-lanes base
        float e0 = __expf((p + bt0) * s0);
        float e1 = __expf((p + bt1) * s1);
        z0 += e0; z1 += e1;                      // identical on all lanes
        acc0.x += v.x * e0; acc0.y += v.y * e0; acc0.z += v.z * e0; acc0.w += v.w * e0;
        acc1.x += v.x * e1; acc1.y += v.y * e1; acc1.z += v.z * e1; acc1.w += v.w * e1;
        if (j == sel) { my_e0 = e0; my_e1 = e1; }
    }

    // batched coalesced e store: lanes 0..31 hold rows row0..row0+31
    if (l < 32) ((float2*)(ws + WS_E))[row0 + l] = make_float2(my_e0, my_e1);
    // per-wave Z partial
    if (l == 0) {
        ws[WS_ZP + blk * 8 + w * 2 + 0] = z0;
        ws[WS_ZP + blk * 8 + w * 2 + 1] = z1;
    }
    // cross-wave U reduce in LDS, one coalesced 2 KB store per block
    int base = w * (D * K) + l * 8;   // column index (4l+j)*2+k within wave region
    ured[base + 0] = acc0.x; ured[base + 1] = acc1.x;
    ured[base + 2] = acc0.y; ured[base + 3] = acc1.y;
    ured[base + 4] = acc0.z; ured[base + 5] = acc1.z;
    ured[base + 6] = acc0.w; ured[base + 7] = acc1.w;
    __syncthreads();
    if (t < 128) {
        float4 a = ((const float4*)(ured       ))[t];
        float4 e = ((const float4*)(ured +  512))[t];
        float4 f = ((const float4*)(ured + 1024))[t];
        float4 g = ((const float4*)(ured + 1536))[t];
        float4 s = make_float4(a.x + e.x + f.x + g.x, a.y + e.y + f.y + g.y,
                               a.z + e.z + f.z + g.z, a.w + e.w + f.w + g.w);
        *(float4*)(ws + WS_UP + blk * (D * K) + 4 * t) = s;
    }
}

// ---- finalize, one block per scene: reduce Z/U, write features + weights ----
__global__ __launch_bounds__(256) void k3_final(const float* __restrict__ ws,
                                                float* __restrict__ out) {
    __shared__ float zsh[2];
    int b = blockIdx.x;
    int t = threadIdx.x;
    int w = t >> 6, l = t & 63;

    // waves 0/1 reduce Z for channel 0/1: 64 partials each (16 blocks x 4 waves)
    if (w < 2) {
        float v = ws[WS_ZP + (b * S1 + (l >> 2)) * 8 + (l & 3) * 2 + w];
#pragma unroll
        for (int m = 32; m > 0; m >>= 1) v += __shfl_xor(v, m);
        if (l == 0) zsh[w] = v;
    }
    __syncthreads();
    float z0 = zsh[0], z1 = zsh[1];

    // features: out[b*512 + j], j = d*2+k
#pragma unroll
    for (int j = t; j < D * K; j += 256) {
        float s = 0.f;
#pragma unroll
        for (int c = 0; c < S1; ++c) s += ws[WS_UP + (b * S1 + c) * (D * K) + j];
        out[b * (D * K) + j] = s / ((j & 1) ? z1 : z0);
    }
    // weights: out2[b*2048 + i]
    const float2* E = (const float2*)(ws + WS_E);
    float2* W = (float2*)(out + B * D * K);
#pragma unroll
    for (int i = t; i < OBJS; i += 256) {
        float2 e = E[b * OBJS + i];
        W[b * OBJS + i] = make_float2(e.x / z0, e.y / z1);
    }
}

extern "C" void kernel_launch(void* const* d_in, const int* in_sizes, int n_in,
                              void* d_out, int out_size, void* d_ws, size_t ws_size,
                              hipStream_t stream) {
    const float* x            = (const float*)d_in[0];   // [N, D]
    const int*   num_objs     = (const int*)d_in[1];     // [B]
    const float* att_shared   = (const float*)d_in[2];   // [1, D]
    const float* att_scale    = (const float*)d_in[3];   // [K, 1]
    const float* channel_bias = (const float*)d_in[4];   // [K, D]
    float* ws  = (float*)d_ws;
    float* out = (float*)d_out;

    // no memset needed: every ws/out location is written before it is read
    k1_partial<<<B * S1, 256, 0, stream>>>(x, ws);
    k2_main<<<B * S1, 256, 0, stream>>>(x, num_objs, att_scale, att_shared,
                                        channel_bias, ws);
    k3_final<<<B, 256, 0, stream>>>(ws, out);
}